// Round 9
// baseline (46.546 us; speedup 1.0000x reference)
//
#include <hip/hip_runtime.h>
#include <hip/hip_bf16.h>
#include <math.h>

#define BB 4
#define CC 64
#define OCN 64
#define HH 128
#define WW 128
#define HW (HH*WW)
#define KKN 9

typedef short short8 __attribute__((ext_vector_type(8)));
typedef float floatx4 __attribute__((ext_vector_type(4)));
typedef unsigned int uintx4 __attribute__((ext_vector_type(4)));

__device__ __forceinline__ short f2bfs(float f) {
    __hip_bfloat16 h = __float2bfloat16(f);
    return *reinterpret_cast<short*>(&h);
}
__device__ __forceinline__ uintx4 as_u4(short8 v) {
    union { short8 s; uintx4 u; } x; x.s = v; return x.u;
}
__device__ __forceinline__ float blo(unsigned d) { return __uint_as_float(d << 16); }
__device__ __forceinline__ float bhi(unsigned d) { return __uint_as_float(d & 0xffff0000u); }

// ---------------- transpose_prep: xt transpose + weight fragment packing, fused -------
__global__ __launch_bounds__(256) void transpose_prep(
    const float* __restrict__ x,
    const float* __restrict__ w_dcn, const float* __restrict__ w_off,
    const float* __restrict__ b_off, const float* __restrict__ w_mask,
    const float* __restrict__ b_mask,
    __hip_bfloat16* __restrict__ xt, __hip_bfloat16* __restrict__ wTf,
    __hip_bfloat16* __restrict__ wOf, float* __restrict__ rebias)
{
    int blk = blockIdx.x;
    int tid = threadIdx.x;
    if (blk < BB * 512) {
        __shared__ float tile[64][33];
        int pixbase = (blk & 511) * 32;
        int b       = blk >> 9;
        const float* xb = x + (size_t)b * CC * HW;
        int p = tid & 31;
        #pragma unroll
        for (int i = 0; i < 8; ++i) {
            int c = (tid >> 5) * 8 + i;
            tile[c][p] = xb[(size_t)c * HW + pixbase + p];
        }
        __syncthreads();
        __hip_bfloat16* xo = xt + ((size_t)b * HW + pixbase) * CC;
        int pixl = tid >> 3;
        int c8t  = tid & 7;
        short8 o;
        #pragma unroll
        for (int i = 0; i < 8; ++i) o[i] = f2bfs(tile[c8t * 8 + i][pixl]);
        *reinterpret_cast<short8*>(&xo[(size_t)pixl * CC + c8t * 8]) = o;
        return;
    }
    int i = (blk - BB * 512) * 256 + tid;
    if (i < 18 * 4 * 64 * 8) {                 // wTf: 18 K-steps x 4 oc-tiles
        int jj = i & 7;
        int l  = (i >> 3) & 63;
        int nt = (i >> 9) & 3;
        int s  = i >> 11;
        int oc = nt * 16 + (l & 15);
        int kk = s * 32 + ((l >> 4) << 3) + jj;
        int c  = kk & 63;
        int kt = kk >> 6;
        wTf[i] = __float2bfloat16(w_dcn[(oc * CC + c) * 9 + kt]);
    }
    int j = i - 18 * 4 * 64 * 8;
    if (j >= 0 && j < 18 * 2 * 64 * 8) {       // wOf: 18 K-steps x 2 oc-tiles (27 used)
        int jj = j & 7;
        int l  = (j >> 3) & 63;
        int nt = (j >> 9) & 1;
        int s  = j >> 10;
        int oc = nt * 16 + (l & 15);
        int kk = s * 32 + ((l >> 4) << 3) + jj;
        int c  = kk & 63;
        int kt = kk >> 6;
        float v = 0.0f;
        if (oc < 18)      v = w_off[(oc * CC + c) * 9 + kt];
        else if (oc < 27) v = w_mask[((oc - 18) * CC + c) * 9 + kt];
        wOf[j] = __float2bfloat16(v);
    }
    int r = j - 18 * 2 * 64 * 8;
    if (r >= 0 && r < 27) rebias[r] = (r < 18) ? b_off[r] : b_mask[r - 18];
}

// ---------------- deform_fused: fully wave-independent, ZERO barriers ----------------
// Block = 4 waves x 16 pixels = 64 px (half row). Each wave, in its own LDS region:
//   Phase A: 3x3 offset/mask conv GEMM [16px x 576]x[576 x 32] (36 MFMA)
//   Phase B: tap setup from wave-local LDS offsets
//   Phase C: bilinear gather (double-buffered 8-load batches) + GEMM (72 MFMA)
// Correctness relies on per-wave in-order LDS + compiler waitcnts only.
#define SCR_OFF  0        // [18][72] bf16, row stride 144 B (A raw tile / C acc tile)
#define TABS_OFF 2592     // [9][16] uint4
#define OFFS_OFF 4896     // [18][16] f32
#define MSL_OFF  6048     // [9][16] f32
#define WSTRIDE  6656

__global__ __launch_bounds__(256, 4) void deform_fused(
    const __hip_bfloat16* __restrict__ xt,
    const __hip_bfloat16* __restrict__ wTf, const __hip_bfloat16* __restrict__ wOf,
    const float* __restrict__ rebias, const float* __restrict__ b_dcn,
    float* __restrict__ off_out, float* __restrict__ out)
{
    __shared__ __align__(16) char lds_all[4 * WSTRIDE];   // 26624 B

    int tid    = threadIdx.x;
    int lane   = tid & 63;
    int wv     = __builtin_amdgcn_readfirstlane(tid >> 6);
    int lane15 = lane & 15;
    int lq     = lane >> 4;       // 0..3
    int px8    = lane >> 3;       // 0..7
    int c8     = lane & 7;        // 0..7
    int co     = c8 * 16;         // byte offset within a pixel's 128B channel row

    int wo0  = (blockIdx.x & 1) * 64;
    int row  = (blockIdx.x >> 1) & (HH - 1);
    int b    = blockIdx.x >> 8;
    int wcol = wo0 + wv * 16;     // this wave's 16-pixel column base

    char*   wb    = lds_all + wv * WSTRIDE;
    char*   scr_b = wb + SCR_OFF;
    uintx4* tabsv = (uintx4*)(wb + TABS_OFF);
    float*  offs  = (float*)(wb + OFFS_OFF);
    float*  msl   = (float*)(wb + MSL_OFF);

    const char* xtb = (const char*)(xt + (size_t)b * HW * CC);
    const short8* wTf8 = (const short8*)wTf;
    const short8* wOf8 = (const short8*)wOf;
    const short8 zero8 = {0,0,0,0,0,0,0,0};

    // ================= Phase A: per-wave offset/mask 3x3 conv =================
    floatx4 accom0 = {0,0,0,0}, accom1 = {0,0,0,0};

#define ALOAD(KY, V0, V1, V2) do { \
    int _y = row + (KY) - 1; \
    bool _yv = (unsigned)_y < (unsigned)HH; \
    int _yc = min(max(_y, 0), HH - 1); \
    { int _xw = wcol + px8 - 1; \
      bool _v = _yv && ((unsigned)_xw < (unsigned)WW); \
      int _xc = min(max(_xw, 0), WW - 1); \
      short8 _t = *(const short8*)(xtb + (((_yc * WW) + _xc) << 7) + co); \
      V0 = _v ? _t : zero8; } \
    { int _xw = wcol + px8 + 7; \
      bool _v = _yv && ((unsigned)_xw < (unsigned)WW); \
      int _xc = min(max(_xw, 0), WW - 1); \
      short8 _t = *(const short8*)(xtb + (((_yc * WW) + _xc) << 7) + co); \
      V1 = _v ? _t : zero8; } \
    { int _xw = wcol + 16 + px8 - 1; \
      bool _v = _yv && ((unsigned)_xw < (unsigned)WW); \
      int _xc = min(max(_xw, 0), WW - 1); \
      short8 _t = *(const short8*)(xtb + (((_yc * WW) + _xc) << 7) + co); \
      V2 = _v ? _t : zero8; } \
} while (0)

#define ADSW(V0, V1, V2) do { \
    *(short8*)(scr_b + px8 * 144 + co) = V0; \
    *(short8*)(scr_b + (px8 + 8) * 144 + co) = V1; \
    if (lane < 16) *(short8*)(scr_b + (16 + px8) * 144 + co) = V2; \
} while (0)

#define AMFMA(KY) do { \
    _Pragma("unroll") \
    for (int s6 = 0; s6 < 6; ++s6) { \
        int kx = s6 >> 1; \
        short8 a = *(const short8*)(scr_b + (lane15 + kx) * 144 + (s6 & 1) * 64 + lq * 16); \
        const short8* bp = wOf8 + (size_t)(((KY) * 6 + s6) * 2) * 64 + lane; \
        accom0 = __builtin_amdgcn_mfma_f32_16x16x32_bf16(a, bp[0],  accom0, 0, 0, 0); \
        accom1 = __builtin_amdgcn_mfma_f32_16x16x32_bf16(a, bp[64], accom1, 0, 0, 0); \
    } \
} while (0)

    {
        short8 va0, va1, va2, vb0, vb1, vb2, vc0, vc1, vc2;
        ALOAD(0, va0, va1, va2);
        ADSW(va0, va1, va2);
        ALOAD(1, vb0, vb1, vb2);
        AMFMA(0);
        ADSW(vb0, vb1, vb2);
        ALOAD(2, vc0, vc1, vc2);
        AMFMA(1);
        ADSW(vc0, vc1, vc2);
        AMFMA(2);
    }
#undef ALOAD
#undef ADSW
#undef AMFMA

    // epilogue A: offsets -> global + wave LDS; sigmoid(mask) -> wave LDS
    {
        // nt = 0: oc = lane15 (0..15, all offset channels)
        float bias0 = rebias[lane15];
        floatx4 o0 = accom0;
        o0[0] += bias0; o0[1] += bias0; o0[2] += bias0; o0[3] += bias0;
        *reinterpret_cast<floatx4*>(
            &off_out[(((size_t)b * 18 + lane15) * HH + row) * WW + wcol + lq * 4]) = o0;
        ((floatx4*)offs)[lane15 * 4 + lq] = o0;
        // nt = 1: oc = 16 + lane15 -> offset ch 16,17 (lane15<2), mask ch 0..8 (2..10)
        int bi = min(16 + lane15, 26);
        float bias1 = rebias[bi];
        if (lane15 < 2) {
            floatx4 o1 = accom1;
            o1[0] += bias1; o1[1] += bias1; o1[2] += bias1; o1[3] += bias1;
            *reinterpret_cast<floatx4*>(
                &off_out[(((size_t)b * 18 + 16 + lane15) * HH + row) * WW + wcol + lq * 4]) = o1;
            ((floatx4*)offs)[(16 + lane15) * 4 + lq] = o1;
        } else if (lane15 < 11) {
            floatx4 m;
            #pragma unroll
            for (int q = 0; q < 4; ++q) m[q] = 1.0f / (1.0f + expf(-(accom1[q] + bias1)));
            ((floatx4*)msl)[(lane15 - 2) * 4 + lq] = m;
        }
    }

    // ================= Phase B: per-wave bilinear tap setup =================
    #pragma unroll
    for (int r = 0; r < 3; ++r) {
        int e = lane + r * 64;
        if (r == 2 && lane >= 16) break;
        int k = e >> 4, p = e & 15;
        float dy = offs[(2 * k) * 16 + p];
        float dx = offs[(2 * k + 1) * 16 + p];
        float m  = msl[k * 16 + p];
        float py = dy + (float)(k / 3) + (float)(row - 1);
        float px_ = dx + (float)(k % 3) + (float)(wcol + p - 1);
        float y0f = floorf(py), x0f = floorf(px_);
        float ly = py - y0f, lx = px_ - x0f;
        int y0 = (int)y0f, x0 = (int)x0f;
        uintx4 rec;
        #pragma unroll
        for (int t = 0; t < 4; ++t) {
            int yi = y0 + (t >> 1), xi = x0 + (t & 1);
            float wy = (t >> 1) ? ly : 1.0f - ly;
            float wx = (t & 1)  ? lx : 1.0f - lx;
            bool valid = ((unsigned)yi < (unsigned)HH) && ((unsigned)xi < (unsigned)WW);
            int yc = min(max(yi, 0), HH - 1);
            int xc = min(max(xi, 0), WW - 1);
            __hip_bfloat16 hw = __float2bfloat16(valid ? wy * wx * m : 0.0f);
            unsigned short wbb = *reinterpret_cast<unsigned short*>(&hw);
            rec[t] = (unsigned)(yc * WW + xc) | ((unsigned)wbb << 16);
        }
        tabsv[k * 16 + p] = rec;
    }

    // ================= Phase C: per-wave gather + GEMM =================
    floatx4 accv0 = {0,0,0,0}, accv1 = {0,0,0,0}, accv2 = {0,0,0,0}, accv3 = {0,0,0,0};

#define CLOAD(K, P0,P1,P2,P3, Q0,Q1,Q2,Q3) do { \
    uintx4 _ua = tabsv[(K) * 16 + px8]; \
    uintx4 _ub = tabsv[(K) * 16 + px8 + 8]; \
    P0 = *(const short8*)(xtb + ((_ua[0] & 0xffffu) << 7) + co); \
    P1 = *(const short8*)(xtb + ((_ua[1] & 0xffffu) << 7) + co); \
    P2 = *(const short8*)(xtb + ((_ua[2] & 0xffffu) << 7) + co); \
    P3 = *(const short8*)(xtb + ((_ua[3] & 0xffffu) << 7) + co); \
    Q0 = *(const short8*)(xtb + ((_ub[0] & 0xffffu) << 7) + co); \
    Q1 = *(const short8*)(xtb + ((_ub[1] & 0xffffu) << 7) + co); \
    Q2 = *(const short8*)(xtb + ((_ub[2] & 0xffffu) << 7) + co); \
    Q3 = *(const short8*)(xtb + ((_ub[3] & 0xffffu) << 7) + co); \
} while (0)

#define CCOMB(K, P0,P1,P2,P3, Q0,Q1,Q2,Q3) do { \
    uintx4 _ua = tabsv[(K) * 16 + px8]; \
    uintx4 _ub = tabsv[(K) * 16 + px8 + 8]; \
    float fA[8] = {0,0,0,0,0,0,0,0}; \
    float fB[8] = {0,0,0,0,0,0,0,0}; \
    { float w = __uint_as_float(_ua[0] & 0xffff0000u); uintx4 d = as_u4(P0); \
      _Pragma("unroll") for (int jq = 0; jq < 4; ++jq) { \
        fA[2*jq] = fmaf(w, blo(d[jq]), fA[2*jq]); fA[2*jq+1] = fmaf(w, bhi(d[jq]), fA[2*jq+1]); } } \
    { float w = __uint_as_float(_ua[1] & 0xffff0000u); uintx4 d = as_u4(P1); \
      _Pragma("unroll") for (int jq = 0; jq < 4; ++jq) { \
        fA[2*jq] = fmaf(w, blo(d[jq]), fA[2*jq]); fA[2*jq+1] = fmaf(w, bhi(d[jq]), fA[2*jq+1]); } } \
    { float w = __uint_as_float(_ua[2] & 0xffff0000u); uintx4 d = as_u4(P2); \
      _Pragma("unroll") for (int jq = 0; jq < 4; ++jq) { \
        fA[2*jq] = fmaf(w, blo(d[jq]), fA[2*jq]); fA[2*jq+1] = fmaf(w, bhi(d[jq]), fA[2*jq+1]); } } \
    { float w = __uint_as_float(_ua[3] & 0xffff0000u); uintx4 d = as_u4(P3); \
      _Pragma("unroll") for (int jq = 0; jq < 4; ++jq) { \
        fA[2*jq] = fmaf(w, blo(d[jq]), fA[2*jq]); fA[2*jq+1] = fmaf(w, bhi(d[jq]), fA[2*jq+1]); } } \
    { float w = __uint_as_float(_ub[0] & 0xffff0000u); uintx4 d = as_u4(Q0); \
      _Pragma("unroll") for (int jq = 0; jq < 4; ++jq) { \
        fB[2*jq] = fmaf(w, blo(d[jq]), fB[2*jq]); fB[2*jq+1] = fmaf(w, bhi(d[jq]), fB[2*jq+1]); } } \
    { float w = __uint_as_float(_ub[1] & 0xffff0000u); uintx4 d = as_u4(Q1); \
      _Pragma("unroll") for (int jq = 0; jq < 4; ++jq) { \
        fB[2*jq] = fmaf(w, blo(d[jq]), fB[2*jq]); fB[2*jq+1] = fmaf(w, bhi(d[jq]), fB[2*jq+1]); } } \
    { float w = __uint_as_float(_ub[2] & 0xffff0000u); uintx4 d = as_u4(Q2); \
      _Pragma("unroll") for (int jq = 0; jq < 4; ++jq) { \
        fB[2*jq] = fmaf(w, blo(d[jq]), fB[2*jq]); fB[2*jq+1] = fmaf(w, bhi(d[jq]), fB[2*jq+1]); } } \
    { float w = __uint_as_float(_ub[3] & 0xffff0000u); uintx4 d = as_u4(Q3); \
      _Pragma("unroll") for (int jq = 0; jq < 4; ++jq) { \
        fB[2*jq] = fmaf(w, blo(d[jq]), fB[2*jq]); fB[2*jq+1] = fmaf(w, bhi(d[jq]), fB[2*jq+1]); } } \
    short8 oA, oB; \
    _Pragma("unroll") for (int jq = 0; jq < 8; ++jq) { oA[jq] = f2bfs(fA[jq]); oB[jq] = f2bfs(fB[jq]); } \
    *(short8*)(scr_b + px8 * 144 + co) = oA; \
    *(short8*)(scr_b + (px8 + 8) * 144 + co) = oB; \
} while (0)

#define CMFMA(K) do { \
    short8 a0 = *(const short8*)(scr_b + lane15 * 144 + lq * 16); \
    short8 a1 = *(const short8*)(scr_b + lane15 * 144 + 64 + lq * 16); \
    const short8* bp = wTf8 + (size_t)(8 * (K)) * 64 + lane; \
    accv0 = __builtin_amdgcn_mfma_f32_16x16x32_bf16(a0, bp[0],   accv0, 0, 0, 0); \
    accv1 = __builtin_amdgcn_mfma_f32_16x16x32_bf16(a0, bp[64],  accv1, 0, 0, 0); \
    accv2 = __builtin_amdgcn_mfma_f32_16x16x32_bf16(a0, bp[128], accv2, 0, 0, 0); \
    accv3 = __builtin_amdgcn_mfma_f32_16x16x32_bf16(a0, bp[192], accv3, 0, 0, 0); \
    accv0 = __builtin_amdgcn_mfma_f32_16x16x32_bf16(a1, bp[256], accv0, 0, 0, 0); \
    accv1 = __builtin_amdgcn_mfma_f32_16x16x32_bf16(a1, bp[320], accv1, 0, 0, 0); \
    accv2 = __builtin_amdgcn_mfma_f32_16x16x32_bf16(a1, bp[384], accv2, 0, 0, 0); \
    accv3 = __builtin_amdgcn_mfma_f32_16x16x32_bf16(a1, bp[448], accv3, 0, 0, 0); \
} while (0)

    {
        short8 xa0, xa1, xa2, xa3, xb0, xb1, xb2, xb3;   // buffer X
        short8 ya0, ya1, ya2, ya3, yb0, yb1, yb2, yb3;   // buffer Y
        CLOAD(0, xa0,xa1,xa2,xa3, xb0,xb1,xb2,xb3);
        CLOAD(1, ya0,ya1,ya2,ya3, yb0,yb1,yb2,yb3);
        CCOMB(0, xa0,xa1,xa2,xa3, xb0,xb1,xb2,xb3); CLOAD(2, xa0,xa1,xa2,xa3, xb0,xb1,xb2,xb3); CMFMA(0);
        CCOMB(1, ya0,ya1,ya2,ya3, yb0,yb1,yb2,yb3); CLOAD(3, ya0,ya1,ya2,ya3, yb0,yb1,yb2,yb3); CMFMA(1);
        CCOMB(2, xa0,xa1,xa2,xa3, xb0,xb1,xb2,xb3); CLOAD(4, xa0,xa1,xa2,xa3, xb0,xb1,xb2,xb3); CMFMA(2);
        CCOMB(3, ya0,ya1,ya2,ya3, yb0,yb1,yb2,yb3); CLOAD(5, ya0,ya1,ya2,ya3, yb0,yb1,yb2,yb3); CMFMA(3);
        CCOMB(4, xa0,xa1,xa2,xa3, xb0,xb1,xb2,xb3); CLOAD(6, xa0,xa1,xa2,xa3, xb0,xb1,xb2,xb3); CMFMA(4);
        CCOMB(5, ya0,ya1,ya2,ya3, yb0,yb1,yb2,yb3); CLOAD(7, ya0,ya1,ya2,ya3, yb0,yb1,yb2,yb3); CMFMA(5);
        CCOMB(6, xa0,xa1,xa2,xa3, xb0,xb1,xb2,xb3); CLOAD(8, xa0,xa1,xa2,xa3, xb0,xb1,xb2,xb3); CMFMA(6);
        CCOMB(7, ya0,ya1,ya2,ya3, yb0,yb1,yb2,yb3);                                             CMFMA(7);
        CCOMB(8, xa0,xa1,xa2,xa3, xb0,xb1,xb2,xb3);                                             CMFMA(8);
    }
#undef CLOAD
#undef CCOMB
#undef CMFMA

    // epilogue C: oc = nt*16 + lane15, pixel = lq*4 + reg within this wave's 16 px
    {
        int pcol = wcol + lq * 4;
        float bias;
        bias = b_dcn[lane15];
        accv0[0] += bias; accv0[1] += bias; accv0[2] += bias; accv0[3] += bias;
        *reinterpret_cast<floatx4*>(&out[(((size_t)b * OCN + lane15) * HH + row) * WW + pcol]) = accv0;
        bias = b_dcn[16 + lane15];
        accv1[0] += bias; accv1[1] += bias; accv1[2] += bias; accv1[3] += bias;
        *reinterpret_cast<floatx4*>(&out[(((size_t)b * OCN + 16 + lane15) * HH + row) * WW + pcol]) = accv1;
        bias = b_dcn[32 + lane15];
        accv2[0] += bias; accv2[1] += bias; accv2[2] += bias; accv2[3] += bias;
        *reinterpret_cast<floatx4*>(&out[(((size_t)b * OCN + 32 + lane15) * HH + row) * WW + pcol]) = accv2;
        bias = b_dcn[48 + lane15];
        accv3[0] += bias; accv3[1] += bias; accv3[2] += bias; accv3[3] += bias;
        *reinterpret_cast<floatx4*>(&out[(((size_t)b * OCN + 48 + lane15) * HH + row) * WW + pcol]) = accv3;
    }
}

extern "C" void kernel_launch(void* const* d_in, const int* in_sizes, int n_in,
                              void* d_out, int out_size, void* d_ws, size_t ws_size,
                              hipStream_t stream) {
    const float* x      = (const float*)d_in[0];
    const float* w_off  = (const float*)d_in[1];
    const float* b_off  = (const float*)d_in[2];
    const float* w_mask = (const float*)d_in[3];
    const float* b_mask = (const float*)d_in[4];
    const float* w_dcn  = (const float*)d_in[5];
    const float* b_dcn  = (const float*)d_in[6];

    float* out     = (float*)d_out;                       // B*OC*H*W
    float* off_out = out + (size_t)BB * OCN * HW;         // B*18*H*W (output 1)

    float* rebias  = (float*)d_ws;                        // 32 f32
    __hip_bfloat16* xt  = (__hip_bfloat16*)(rebias + 32); // B*HW*C bf16
    __hip_bfloat16* wTf = xt + (size_t)BB * HW * CC;      // 18*4*64*8 bf16
    __hip_bfloat16* wOf = wTf + 18 * 4 * 64 * 8;          // 18*2*64*8 bf16

    int prep_total  = 18 * 4 * 64 * 8 + 18 * 2 * 64 * 8 + 27;
    int prep_blocks = (prep_total + 255) / 256;           // 217
    transpose_prep<<<BB * 512 + prep_blocks, 256, 0, stream>>>(
        x, w_dcn, w_off, b_off, w_mask, b_mask, xt, wTf, wOf, rebias);

    deform_fused<<<BB * HH * 2, 256, 0, stream>>>(
        xt, wTf, wOf, rebias, b_dcn, off_out, out);
}

// Round 10
// 39.963 us; speedup vs baseline: 1.1647x; 1.1647x over previous
//
#include <hip/hip_runtime.h>
#include <hip/hip_bf16.h>
#include <math.h>

#define BB 4
#define CC 64
#define OCN 64
#define HH 128
#define WW 128
#define HW (HH*WW)
#define KKN 9
#define APAD 200          // LDS row stride (bf16) for accs tile

typedef short short8 __attribute__((ext_vector_type(8)));
typedef short short4v __attribute__((ext_vector_type(4)));
typedef float floatx4 __attribute__((ext_vector_type(4)));
typedef unsigned int uintx4 __attribute__((ext_vector_type(4)));

__device__ __forceinline__ float bf2f_us(unsigned short u) {
    return __uint_as_float(((unsigned)u) << 16);
}
__device__ __forceinline__ short f2bfs(float f) {
    __hip_bfloat16 h = __float2bfloat16(f);
    return *reinterpret_cast<short*>(&h);
}
__device__ __forceinline__ uintx4 as_u4(short8 v) {
    union { short8 s; uintx4 u; } x; x.s = v; return x.u;
}
__device__ __forceinline__ float blo(unsigned d) { return __uint_as_float(d << 16); }
__device__ __forceinline__ float bhi(unsigned d) { return __uint_as_float(d & 0xffff0000u); }

// ---------------- transpose_prep: xt transpose + weight fragment packing (= round 8) ---
__global__ __launch_bounds__(256) void transpose_prep(
    const float* __restrict__ x,
    const float* __restrict__ w_dcn, const float* __restrict__ w_off,
    const float* __restrict__ b_off, const float* __restrict__ w_mask,
    const float* __restrict__ b_mask,
    __hip_bfloat16* __restrict__ xt, __hip_bfloat16* __restrict__ wTf,
    __hip_bfloat16* __restrict__ wOf, float* __restrict__ rebias)
{
    int blk = blockIdx.x;
    int tid = threadIdx.x;
    if (blk < BB * 512) {
        __shared__ float tile[64][33];
        int pixbase = (blk & 511) * 32;
        int b       = blk >> 9;
        const float* xb = x + (size_t)b * CC * HW;
        int p = tid & 31;
        #pragma unroll
        for (int i = 0; i < 8; ++i) {
            int c = (tid >> 5) * 8 + i;
            tile[c][p] = xb[(size_t)c * HW + pixbase + p];
        }
        __syncthreads();
        __hip_bfloat16* xo = xt + ((size_t)b * HW + pixbase) * CC;
        int pixl = tid >> 3;
        int c8t  = tid & 7;
        short8 o;
        #pragma unroll
        for (int i = 0; i < 8; ++i) o[i] = f2bfs(tile[c8t * 8 + i][pixl]);
        *reinterpret_cast<short8*>(&xo[(size_t)pixl * CC + c8t * 8]) = o;
        return;
    }
    int i = (blk - BB * 512) * 256 + tid;
    if (i < 18 * 4 * 64 * 8) {                 // wTf: 18 K-steps x 4 oc-tiles
        int jj = i & 7;
        int l  = (i >> 3) & 63;
        int nt = (i >> 9) & 3;
        int s  = i >> 11;
        int oc = nt * 16 + (l & 15);
        int kk = s * 32 + ((l >> 4) << 3) + jj;
        int c  = kk & 63;
        int kt = kk >> 6;
        wTf[i] = __float2bfloat16(w_dcn[(oc * CC + c) * 9 + kt]);
    }
    int j = i - 18 * 4 * 64 * 8;
    if (j >= 0 && j < 18 * 2 * 64 * 8) {       // wOf: 18 K-steps x 2 oc-tiles (27 used)
        int jj = j & 7;
        int l  = (j >> 3) & 63;
        int nt = (j >> 9) & 1;
        int s  = j >> 10;
        int oc = nt * 16 + (l & 15);
        int kk = s * 32 + ((l >> 4) << 3) + jj;
        int c  = kk & 63;
        int kt = kk >> 6;
        float v = 0.0f;
        if (oc < 18)      v = w_off[(oc * CC + c) * 9 + kt];
        else if (oc < 27) v = w_mask[((oc - 18) * CC + c) * 9 + kt];
        wOf[j] = __float2bfloat16(v);
    }
    int r = j - 18 * 2 * 64 * 8;
    if (r >= 0 && r < 27) rebias[r] = (r < 18) ? b_off[r] : b_mask[r - 18];
}

// ---------------- deform_fused: 64 px/block (half row), 4 waves, R8 schedule ----------
// Phase A: offset/mask conv GEMM; wave = (nt = wv&1, ph = wv>>1 -> pgs ph*2, ph*2+1).
// Phase B: tap setup from LDS (bf16 offsets/mask).
// Phase C: gather as 18 double-buffered groups (k, half); MFMA wave = oc-tile, 4 pgs.
__global__ __launch_bounds__(256, 4) void deform_fused(
    const __hip_bfloat16* __restrict__ xt,
    const __hip_bfloat16* __restrict__ wTf, const __hip_bfloat16* __restrict__ wOf,
    const float* __restrict__ rebias, const float* __restrict__ b_dcn,
    float* __restrict__ off_out, float* __restrict__ out)
{
    __shared__ __align__(16) __hip_bfloat16 accs[64][APAD];   // 25600 B
    __shared__ uintx4 tabs[KKN][64];                          // 9216 B
    __shared__ __hip_bfloat16 offs_l[18][68];                 // 2448 B
    __shared__ __hip_bfloat16 ms_l[KKN][68];                  // 1224 B

    int tid    = threadIdx.x;
    int lane   = tid & 63;
    int wv     = __builtin_amdgcn_readfirstlane(tid >> 6);
    int lane15 = lane & 15;
    int lq     = lane >> 4;       // 0..3
    int nt     = wv & 1;          // phase-A oc-tile
    int ph     = wv >> 1;         // phase-A pixel-half
    int pix    = tid >> 3;        // 0..31 (gather/staging pixel within half)
    int c8     = tid & 7;         // 0..7
    int co     = c8 * 16;         // byte offset within a pixel's 128B channel row
    int kreg   = lq << 3;

    int wo0 = (blockIdx.x & 1) * 64;
    int row = (blockIdx.x >> 1) & (HH - 1);
    int b   = blockIdx.x >> 8;

    const char* xtb = (const char*)(xt + (size_t)b * HW * CC);
    const short8* wTf8 = (const short8*)wTf;
    const short8* wOf8 = (const short8*)wOf;
    const short8 zero8 = {0,0,0,0,0,0,0,0};

    // ================= Phase A: offset/mask 3x3 conv GEMM =================
    floatx4 accomA[2] = {{0,0,0,0},{0,0,0,0}};
    for (int chunk = 0; chunk < 3; ++chunk) {
        int y = row + chunk - 1;
        bool yvalid = (unsigned)y < (unsigned)HH;
        int yc = min(max(y, 0), HH - 1);
        short8 v[2][3];
        #pragma unroll
        for (int h = 0; h < 2; ++h) {
            #pragma unroll
            for (int kl = 0; kl < 3; ++kl) {
                int xw = wo0 + h * 32 + pix + kl - 1;
                bool valid = yvalid && ((unsigned)xw < (unsigned)WW);
                int xc = min(max(xw, 0), WW - 1);
                short8 t = *(const short8*)(xtb + (((yc * WW) + xc) << 7) + co);
                v[h][kl] = valid ? t : zero8;
            }
        }
        #pragma unroll
        for (int h = 0; h < 2; ++h)
            #pragma unroll
            for (int kl = 0; kl < 3; ++kl)
                *reinterpret_cast<short8*>(&accs[h * 32 + pix][kl * 64 + c8 * 8]) = v[h][kl];
        __syncthreads();

        #pragma unroll
        for (int step = 0; step < 6; ++step) {
            int s = chunk * 6 + step;
            short8 bfrag = wOf8[(size_t)(s * 2 + nt) * 64 + lane];
            #pragma unroll
            for (int q = 0; q < 2; ++q) {
                int pg = ph * 2 + q;
                short8 a = *reinterpret_cast<const short8*>(&accs[pg * 16 + lane15][step * 32 + kreg]);
                accomA[q] = __builtin_amdgcn_mfma_f32_16x16x32_bf16(a, bfrag, accomA[q], 0, 0, 0);
            }
        }
        __syncthreads();
    }

    // epilogue A: offsets -> global (f32, output 1) + LDS bf16; sigmoid(mask) -> LDS bf16
    #pragma unroll
    for (int q = 0; q < 2; ++q) {
        int pg = ph * 2 + q;
        int pcl = pg * 16 + lq * 4;          // 0..60, mult of 4
        int oc = nt * 16 + lane15;
        if (oc < 18) {
            float bias = rebias[oc];
            floatx4 o = accomA[q];
            o[0] += bias; o[1] += bias; o[2] += bias; o[3] += bias;
            *reinterpret_cast<floatx4*>(
                &off_out[(((size_t)b * 18 + oc) * HH + row) * WW + wo0 + pcl]) = o;
            short4v ob = { f2bfs(o[0]), f2bfs(o[1]), f2bfs(o[2]), f2bfs(o[3]) };
            *reinterpret_cast<short4v*>(&offs_l[oc][pcl]) = ob;
        } else if (oc < 27) {
            float bias = rebias[oc];
            short4v mb;
            #pragma unroll
            for (int t = 0; t < 4; ++t)
                mb[t] = f2bfs(1.0f / (1.0f + expf(-(accomA[q][t] + bias))));
            *reinterpret_cast<short4v*>(&ms_l[oc - 18][pcl]) = mb;
        }
    }
    __syncthreads();

    // ================= Phase B: bilinear tap setup (9 k x 64 px) =================
    for (int e = tid; e < KKN * 64; e += 256) {
        int k = e >> 6, p = e & 63;
        float dy = bf2f_us(*(const unsigned short*)&offs_l[2 * k][p]);
        float dx = bf2f_us(*(const unsigned short*)&offs_l[2 * k + 1][p]);
        float m  = bf2f_us(*(const unsigned short*)&ms_l[k][p]);
        float py = dy + (float)(k / 3) + (float)(row - 1);
        float px = dx + (float)(k % 3) + (float)(wo0 + p - 1);
        float y0f = floorf(py), x0f = floorf(px);
        float ly = py - y0f, lx = px - x0f;
        int y0 = (int)y0f, x0 = (int)x0f;
        uintx4 rec;
        #pragma unroll
        for (int t = 0; t < 4; ++t) {
            int yi = y0 + (t >> 1), xi = x0 + (t & 1);
            float wy = (t >> 1) ? ly : 1.0f - ly;
            float wx = (t & 1)  ? lx : 1.0f - lx;
            bool valid = ((unsigned)yi < (unsigned)HH) && ((unsigned)xi < (unsigned)WW);
            int yc2 = min(max(yi, 0), HH - 1);
            int xc2 = min(max(xi, 0), WW - 1);
            __hip_bfloat16 hw = __float2bfloat16(valid ? wy * wx * m : 0.0f);
            unsigned short wb = *reinterpret_cast<unsigned short*>(&hw);
            rec[t] = (unsigned)(yc2 * WW + xc2) | ((unsigned)wb << 16);
        }
        tabs[k][p] = rec;
    }
    __syncthreads();

    // ================= Phase C: gather (18 groups, dbuf) + MFMA GEMM =================
    short8 buf[2][4];
    uintx4 tb[2];
    floatx4 accv[4] = {{0,0,0,0},{0,0,0,0},{0,0,0,0},{0,0,0,0}};

#define ISSUE(G) do { \
    uintx4 _t = tabs[(G) >> 1][pix + ((G) & 1) * 32]; \
    tb[(G) & 1] = _t; \
    buf[(G) & 1][0] = *(const short8*)(xtb + ((_t[0] & 0xffffu) << 7) + co); \
    buf[(G) & 1][1] = *(const short8*)(xtb + ((_t[1] & 0xffffu) << 7) + co); \
    buf[(G) & 1][2] = *(const short8*)(xtb + ((_t[2] & 0xffffu) << 7) + co); \
    buf[(G) & 1][3] = *(const short8*)(xtb + ((_t[3] & 0xffffu) << 7) + co); \
} while (0)

#define COMBINE(G) do { \
    float fA[8] = {0,0,0,0,0,0,0,0}; \
    _Pragma("unroll") \
    for (int t = 0; t < 4; ++t) { \
        float wt = __uint_as_float(tb[(G) & 1][t] & 0xffff0000u); \
        uintx4 dA = as_u4(buf[(G) & 1][t]); \
        _Pragma("unroll") \
        for (int jq = 0; jq < 4; ++jq) { \
            fA[2 * jq]     = fmaf(wt, blo(dA[jq]), fA[2 * jq]); \
            fA[2 * jq + 1] = fmaf(wt, bhi(dA[jq]), fA[2 * jq + 1]); \
        } \
    } \
    short8 oA; \
    _Pragma("unroll") \
    for (int jq = 0; jq < 8; ++jq) { oA[jq] = f2bfs(fA[jq]); } \
    *reinterpret_cast<short8*>( \
        &accs[((G) & 1) * 32 + pix][(((G) >> 1) % 3) * 64 + c8 * 8]) = oA; \
} while (0)

#define CMFMA(CH) do { \
    _Pragma("unroll") \
    for (int step = 0; step < 6; ++step) { \
        int s = (CH) * 6 + step; \
        short8 bfrag = wTf8[(size_t)(s * 4 + wv) * 64 + lane]; \
        _Pragma("unroll") \
        for (int pg = 0; pg < 4; ++pg) { \
            short8 a = *reinterpret_cast<const short8*>(&accs[pg * 16 + lane15][step * 32 + kreg]); \
            accv[pg] = __builtin_amdgcn_mfma_f32_16x16x32_bf16(a, bfrag, accv[pg], 0, 0, 0); \
        } \
    } \
} while (0)

    ISSUE(0); ISSUE(1);
    // ---- chunk 0 (groups 0..5) ----
    COMBINE(0); ISSUE(2);
    COMBINE(1); ISSUE(3);
    COMBINE(2); ISSUE(4);
    COMBINE(3); ISSUE(5);
    COMBINE(4); COMBINE(5);
    __syncthreads();
    ISSUE(6); ISSUE(7);             // prefetch chunk1, flies across MFMA + raw barrier
    CMFMA(0);
    asm volatile("s_waitcnt lgkmcnt(0)" ::: "memory");
    __builtin_amdgcn_s_barrier();   // raw: does NOT drain vmcnt
    // ---- chunk 1 (groups 6..11) ----
    COMBINE(6); ISSUE(8);
    COMBINE(7); ISSUE(9);
    COMBINE(8); ISSUE(10);
    COMBINE(9); ISSUE(11);
    COMBINE(10); COMBINE(11);
    __syncthreads();
    ISSUE(12); ISSUE(13);
    CMFMA(1);
    asm volatile("s_waitcnt lgkmcnt(0)" ::: "memory");
    __builtin_amdgcn_s_barrier();
    // ---- chunk 2 (groups 12..17) ----
    COMBINE(12); ISSUE(14);
    COMBINE(13); ISSUE(15);
    COMBINE(14); ISSUE(16);
    COMBINE(15); ISSUE(17);
    COMBINE(16); COMBINE(17);
    __syncthreads();
    CMFMA(2);

#undef ISSUE
#undef COMBINE
#undef CMFMA

    // epilogue C: wave wv owns oc-tile wv; D: col=lane15 (oc), row=lq*4+reg (pixel)
    {
        int oc = wv * 16 + lane15;
        float bias = b_dcn[oc];
        #pragma unroll
        for (int pg = 0; pg < 4; ++pg) {
            int pcol = wo0 + pg * 16 + lq * 4;
            floatx4 o = accv[pg];
            o[0] += bias; o[1] += bias; o[2] += bias; o[3] += bias;
            *reinterpret_cast<floatx4*>(&out[(((size_t)b * OCN + oc) * HH + row) * WW + pcol]) = o;
        }
    }
}

extern "C" void kernel_launch(void* const* d_in, const int* in_sizes, int n_in,
                              void* d_out, int out_size, void* d_ws, size_t ws_size,
                              hipStream_t stream) {
    const float* x      = (const float*)d_in[0];
    const float* w_off  = (const float*)d_in[1];
    const float* b_off  = (const float*)d_in[2];
    const float* w_mask = (const float*)d_in[3];
    const float* b_mask = (const float*)d_in[4];
    const float* w_dcn  = (const float*)d_in[5];
    const float* b_dcn  = (const float*)d_in[6];

    float* out     = (float*)d_out;                       // B*OC*H*W
    float* off_out = out + (size_t)BB * OCN * HW;         // B*18*H*W (output 1)

    float* rebias  = (float*)d_ws;                        // 32 f32
    __hip_bfloat16* xt  = (__hip_bfloat16*)(rebias + 32); // B*HW*C bf16
    __hip_bfloat16* wTf = xt + (size_t)BB * HW * CC;      // 18*4*64*8 bf16
    __hip_bfloat16* wOf = wTf + 18 * 4 * 64 * 8;          // 18*2*64*8 bf16

    int prep_total  = 18 * 4 * 64 * 8 + 18 * 2 * 64 * 8 + 27;
    int prep_blocks = (prep_total + 255) / 256;           // 217
    transpose_prep<<<BB * 512 + prep_blocks, 256, 0, stream>>>(
        x, w_dcn, w_off, b_off, w_mask, b_mask, xt, wTf, wOf, rebias);

    deform_fused<<<BB * HH * 2, 256, 0, stream>>>(
        xt, wTf, wOf, rebias, b_dcn, off_out, out);
}